// Round 1
// baseline (710.369 us; speedup 1.0000x reference)
//
#include <hip/hip_runtime.h>
#include <stdint.h>

typedef __attribute__((ext_vector_type(8))) _Float16 f16x8;
typedef __attribute__((ext_vector_type(4))) float f32x4;

#define N_NODES 4096
#define N_EDGES 32768

__device__ __forceinline__ float sigm(float x) { return 1.f / (1.f + __expf(-x)); }

// pack 8 consecutive f32 -> f16x8 (RNE)
__device__ __forceinline__ f16x8 packh8(const float* p) {
  f16x8 r;
#pragma unroll
  for (int i = 0; i < 8; ++i) r[i] = (_Float16)p[i];
  return r;
}

// ---------------------------------------------------------------------------
// prep (merged): blocks 0..127  -> WnnT[n][k] fp16 from Wnn[k][n] f32
//                blocks 128..319 -> We1T / We2T fp16 transposes
// ---------------------------------------------------------------------------
__global__ void prep_all(const float* __restrict__ Wnn,
                         const float* __restrict__ We1,
                         const float* __restrict__ We2,
                         _Float16* __restrict__ WnnT,
                         _Float16* __restrict__ We1T,
                         _Float16* __restrict__ We2T) {
  __shared__ float tile[128][33];
  const int b = blockIdx.x, t = threadIdx.x;
  if (b < 128) {
    const int nb = b * 32;
    for (int i = 0; i < 16; ++i) {
      int g = i * 256 + t;          // 4096 = 128k x 32n
      int k = g >> 5, j = g & 31;
      tile[k][j] = Wnn[(size_t)k * 4096 + nb + j];
    }
    __syncthreads();
    for (int i = 0; i < 16; ++i) {
      int g = i * 256 + t;
      int j = g >> 7, k = g & 127;
      WnnT[(size_t)(nb + j) * 128 + k] = (_Float16)tile[k][j];
    }
  } else {
    int idx = (b - 128) * 256 + t;   // < 49152
    if (idx < 32768) {
      int n = idx >> 8, k = idx & 255;
      We1T[idx] = (_Float16)We1[(size_t)k * 128 + n];
    } else {
      int j = idx - 32768;
      int n = j >> 7, k = j & 127;
      We2T[j] = (_Float16)We2[(size_t)k * 128 + n];
    }
  }
}

// ---------------------------------------------------------------------------
// CSR build (once per launch; edge_index is launch-constant)
// ---------------------------------------------------------------------------
__global__ void csr_zero(int* __restrict__ rowcnt) {
  rowcnt[blockIdx.x * 256 + threadIdx.x] = 0;
}
__global__ void csr_count(const int* __restrict__ eidx, int* __restrict__ rowcnt) {
  int e = blockIdx.x * 256 + threadIdx.x;
  atomicAdd(&rowcnt[eidx[N_EDGES + e]], 1);
}
__global__ void csr_scan(const int* __restrict__ rowcnt,
                         int* __restrict__ rowptr, int* __restrict__ cursor) {
  __shared__ int part[1024];
  const int t = threadIdx.x;
  const int base = t * 4;
  int s0 = rowcnt[base], s1 = rowcnt[base + 1], s2 = rowcnt[base + 2], s3 = rowcnt[base + 3];
  int sum = s0 + s1 + s2 + s3;
  part[t] = sum;
  __syncthreads();
  for (int off = 1; off < 1024; off <<= 1) {
    int v = (t >= off) ? part[t - off] : 0;
    __syncthreads();
    part[t] += v;
    __syncthreads();
  }
  int excl = part[t] - sum;
  int p0 = excl, p1 = excl + s0, p2 = excl + s0 + s1, p3 = excl + s0 + s1 + s2;
  rowptr[base] = p0; rowptr[base + 1] = p1; rowptr[base + 2] = p2; rowptr[base + 3] = p3;
  cursor[base] = p0; cursor[base + 1] = p1; cursor[base + 2] = p2; cursor[base + 3] = p3;
  if (t == 0) rowptr[4096] = N_EDGES;
}
__global__ void csr_fill(const int* __restrict__ eidx, int* __restrict__ cursor,
                         int* __restrict__ eids) {
  int e = blockIdx.x * 256 + threadIdx.x;
  int slot = atomicAdd(&cursor[eidx[N_EDGES + e]], 1);
  eids[slot] = e;
}

// ---------------------------------------------------------------------------
// proj_node: h = relu(node_feats @ W_p + b_p) -> hid f32 (in d_out)
// ---------------------------------------------------------------------------
__global__ void proj_node_f(const float* __restrict__ nf,
                            const float* __restrict__ Wp,
                            const float* __restrict__ bp,
                            float* __restrict__ h) {
  int idx = blockIdx.x * 256 + threadIdx.x;
  int n = idx >> 6, c = idx & 63;
  float acc = bp[c];
  for (int k = 0; k < 64; ++k)
    acc = fmaf(nf[n * 64 + k], Wp[k * 64 + c], acc);
  h[idx] = fmaxf(acc, 0.f);
}

// ---------------------------------------------------------------------------
// proj_edge: e = relu(edge_attr @ W_pe + b_pe); Wpe cached in LDS; 32 e/block.
// ---------------------------------------------------------------------------
__launch_bounds__(256)
__global__ void proj_edge_f2(const float* __restrict__ ea,
                             const float* __restrict__ Wpe,
                             const float* __restrict__ bpe,
                             float* __restrict__ e) {
  __shared__ float sw[16 * 128];
  __shared__ float sb[128];
  __shared__ float sa[32][17];
  const int t = threadIdx.x;
  const int ebase = blockIdx.x * 32;
  for (int g = t; g < 2048; g += 256) sw[g] = Wpe[g];
  if (t < 128) sb[t] = bpe[t];
  for (int g = t; g < 512; g += 256) {
    int r = g >> 4, k = g & 15;
    sa[r][k] = ea[(size_t)(ebase + r) * 16 + k];
  }
  __syncthreads();
  int c = t & 127, eg = t >> 7;
  float wc[16];
#pragma unroll
  for (int k = 0; k < 16; ++k) wc[k] = sw[k * 128 + c];
  float bv = sb[c];
#pragma unroll
  for (int i = 0; i < 16; ++i) {
    int ee = eg * 16 + i;
    float acc = bv;
#pragma unroll
    for (int k = 0; k < 16; ++k) acc = fmaf(sa[ee][k], wc[k], acc);
    e[(size_t)(ebase + ee) * 128 + c] = fmaxf(acc, 0.f);
  }
}

// ---------------------------------------------------------------------------
// fused_msg (MFMA fp16 v9): 512 blocks x 512 threads, 64 edges/block.
// R13 theory: R12's counters showed no pipe >20% busy and Occupancy 20.7%
// (grid = 256 blocks = 1 block/CU = 2 waves/SIMD) -> latency-bound, wave-
// starved. v9 splits the d-sweep ACROSS waves: 8 waves = 4 f-groups x 2
// d-halves, each wave does 8 dgs over 64 edges; partial msg combined via a
// small LDS buffer. Grid 512 blocks -> 2 blocks/CU, 4 waves/SIMD, and the
// two independent blocks' barriers decouple (one stages while the other
// computes). LDS 50.7 KB/block, VGPR capped 128 via launch_bounds(512,4).
// Kept from v8: per-wave dg rotation, opaque A-LDS offset, bnn folded into
// MFMA C-init, XOR-swizzled Ae.
// ---------------------------------------------------------------------------
__launch_bounds__(512, 4)
__global__ void fused_msg_m(const float* __restrict__ ebf,
                            const float* __restrict__ hid,
                            const _Float16* __restrict__ WnnT,
                            const float* __restrict__ bnn,
                            const int* __restrict__ eidx,
                            _Float16* __restrict__ msgbuf) {
  __shared__ __align__(16) _Float16 Ae[64 * 128];  // 16,384 B, XOR-swizzled
  __shared__ __align__(16) float Hs[64 * 68];      // 17,408 B  Hs[d*68+e]
  __shared__ __align__(16) float Rd[64 * 66];      // 16,896 B  d-half reduce
  const int t = threadIdx.x;       // 0..511
  const int w = t >> 6, l = t & 63, l15 = l & 15, q = l >> 4;
  const int fw = w & 3;            // f cols: fw*16 + l15
  const int dh = w >> 2;           // d half: d in [dh*32, dh*32+32)
  const int ebase = blockIdx.x * 64;
  const int rot = (blockIdx.x * 2 + w) & 7;   // per-WAVE rotation

  // stage Hs (transposed): 64 e x 16 d-quads
#pragma unroll
  for (int i = 0; i < 2; ++i) {
    int g = i * 512 + t;
    int e = g >> 4, d4 = g & 15;
    int r = eidx[ebase + e];
    float4 v = *(const float4*)&hid[(size_t)r * 64 + d4 * 4];
    Hs[(d4 * 4 + 0) * 68 + e] = v.x;
    Hs[(d4 * 4 + 1) * 68 + e] = v.y;
    Hs[(d4 * 4 + 2) * 68 + e] = v.z;
    Hs[(d4 * 4 + 3) * 68 + e] = v.w;
  }
  // stage Ae: 64 edges x 128 k, f32 -> fp16 once, XOR-swizzled 16B blocks
#pragma unroll
  for (int i = 0; i < 2; ++i) {
    int g = i * 512 + t;           // 1024 = 64 e x 16 groups of 8 halves
    int e = g >> 4, kg = g & 15;
    f16x8 v = packh8(&ebf[(size_t)(ebase + e) * 128 + kg * 8]);
    int kgp = kg ^ (e & 15);
    *(f16x8*)&Ae[e * 128 + kgp * 8] = v;
  }

  float msg[4][4];
#pragma unroll
  for (int m = 0; m < 4; ++m)
#pragma unroll
    for (int rr = 0; rr < 4; ++rr) msg[m][rr] = 0.f;

  __syncthreads();

  // opaque zero: A-LDS addresses depend on it -> reads can't be hoisted out
  // of the dg loop (avoids the 64-VGPR A-hoist), but B loads CAN pipeline.
  int aoff = 0;
  asm volatile("" : "+v"(aoff));

  // B fragment base: lane row within chunk = fw*16+l15, k-offset q*8
  const _Float16* wb = WnnT + (size_t)(fw * 16 + l15) * 128 + q * 8;

#pragma unroll 1
  for (int dgi = 0; dgi < 8; ++dgi) {
    const int dgr = dh * 8 + ((dgi + rot) & 7);   // this wave's d-half sweep
    f16x8 bb[4][4];
#pragma unroll
    for (int c = 0; c < 4; ++c) {
      const _Float16* p = wb + (size_t)(dgr * 4 + c) * 8192;
#pragma unroll
      for (int kk = 0; kk < 4; ++kk) bb[c][kk] = *(const f16x8*)(p + kk * 32);
    }
    float bnv[4];
#pragma unroll
    for (int c = 0; c < 4; ++c) bnv[c] = bnn[(dgr * 4 + c) * 64 + fw * 16 + l15];

#pragma unroll
    for (int m = 0; m < 4; ++m) {
      const int arow = (m * 16 + l15) * 128 + aoff;
      f32x4 C[4];
#pragma unroll
      for (int c = 0; c < 4; ++c)
        C[c] = (f32x4){bnv[c], bnv[c], bnv[c], bnv[c]};   // bias pre-loaded
#pragma unroll
      for (int kk = 0; kk < 4; ++kk) {
        int kgp = (kk * 4 + q) ^ l15;   // e&15 == l15 for this wave's A rows
        f16x8 a = *(const f16x8*)&Ae[arow + kgp * 8];
#pragma unroll
        for (int c = 0; c < 4; ++c)
          C[c] = __builtin_amdgcn_mfma_f32_16x16x32_f16(a, bb[c][kk], C[c], 0, 0, 0);
      }
#pragma unroll
      for (int c = 0; c < 4; ++c) {
        int d = dgr * 4 + c;
        float4 hv = *(const float4*)&Hs[d * 68 + m * 16 + q * 4];
        msg[m][0] = fmaf(hv.x, fmaxf(C[c][0], 0.f), msg[m][0]);
        msg[m][1] = fmaf(hv.y, fmaxf(C[c][1], 0.f), msg[m][1]);
        msg[m][2] = fmaf(hv.z, fmaxf(C[c][2], 0.f), msg[m][2]);
        msg[m][3] = fmaf(hv.w, fmaxf(C[c][3], 0.f), msg[m][3]);
      }
    }
  }

  // cross-d-half reduction via LDS, then plain fp16 stores -> msgbuf[e][f]
  if (dh == 1) {
#pragma unroll
    for (int m = 0; m < 4; ++m)
#pragma unroll
      for (int rr = 0; rr < 4; ++rr)
        Rd[(m * 16 + q * 4 + rr) * 66 + fw * 16 + l15] = msg[m][rr];
  }
  __syncthreads();
  if (dh == 0) {
#pragma unroll
    for (int m = 0; m < 4; ++m)
#pragma unroll
      for (int rr = 0; rr < 4; ++rr) {
        int er = m * 16 + q * 4 + rr;
        float v = msg[m][rr] + Rd[er * 66 + fw * 16 + l15];
        msgbuf[(size_t)(ebase + er) * 64 + fw * 16 + l15] = (_Float16)v;
      }
  }
}

// ---------------------------------------------------------------------------
// node_update_g: agg via CSR gather of msgbuf; m = relu(agg + h@W_root+b);
// GRU gates gate-column-per-thread (weights read once per block); h (f32,
// d_out) updated in place. Block = 16 nodes, 256 threads.
// ---------------------------------------------------------------------------
__launch_bounds__(256)
__global__ void node_update_g(const _Float16* __restrict__ msgbuf,
                              const int* __restrict__ rowptr,
                              const int* __restrict__ eids,
                              float* __restrict__ hid,
                              const float* __restrict__ Wroot,
                              const float* __restrict__ bconv,
                              const float* __restrict__ wih,
                              const float* __restrict__ whh,
                              const float* __restrict__ bih,
                              const float* __restrict__ bhh) {
  __shared__ __align__(16) float shT[64 * 20];   // h^T  [k][nl], stride 20
  __shared__ __align__(16) float smT[64 * 20];   // m^T  [k][nl]
  __shared__ __align__(16) float sg[16 * 384];   // gates
  __shared__ __align__(16) float sW[64 * 64];    // Wroot
  const int t = threadIdx.x;
  const int nb = blockIdx.x * 16;

  // stage Wroot (f32, 16KB)
#pragma unroll
  for (int i = 0; i < 4; ++i) {
    int g = i * 256 + t;
    *(float4*)&sW[g * 4] = *(const float4*)&Wroot[g * 4];
  }
  // stage h transposed
#pragma unroll
  for (int i = 0; i < 4; ++i) {
    int idx = i * 256 + t;
    int nl = idx >> 6, dc = idx & 63;
    shT[dc * 20 + nl] = hid[(size_t)(nb + nl) * 64 + dc];
  }
  __syncthreads();

  // phase 1: gather msg + root matmul -> m (write transposed)
#pragma unroll
  for (int i = 0; i < 4; ++i) {
    int idx = i * 256 + t;
    int nl = idx >> 6, dc = idx & 63;
    int n = nb + nl;
    float acc = bconv[dc];
    int r0 = rowptr[n], r1 = rowptr[n + 1];
    for (int j = r0; j < r1; ++j)
      acc += (float)msgbuf[(size_t)eids[j] * 64 + dc];
    for (int k = 0; k < 64; ++k)
      acc = fmaf(shT[k * 20 + nl], sW[k * 64 + dc], acc);
    smT[dc * 20 + nl] = fmaxf(acc, 0.f);
  }
  __syncthreads();

  // phase 2: gates — thread owns one gate column, accumulates 16 nodes in regs
  for (int p = 0; p < 2; ++p) {
    int j2 = p * 256 + t;
    if (j2 < 384) {
      bool is_ih = (j2 < 192);
      int col = is_ih ? j2 : j2 - 192;
      const float* W = is_ih ? wih : whh;
      float bias = is_ih ? bih[col] : bhh[col];
      const float* inT = is_ih ? smT : shT;
      float a[16];
#pragma unroll
      for (int nl = 0; nl < 16; ++nl) a[nl] = bias;
      for (int k = 0; k < 64; ++k) {
        float wv = W[k * 192 + col];
        float4 v0 = *(const float4*)&inT[k * 20 + 0];
        float4 v1 = *(const float4*)&inT[k * 20 + 4];
        float4 v2 = *(const float4*)&inT[k * 20 + 8];
        float4 v3 = *(const float4*)&inT[k * 20 + 12];
        a[0]  = fmaf(v0.x, wv, a[0]);  a[1]  = fmaf(v0.y, wv, a[1]);
        a[2]  = fmaf(v0.z, wv, a[2]);  a[3]  = fmaf(v0.w, wv, a[3]);
        a[4]  = fmaf(v1.x, wv, a[4]);  a[5]  = fmaf(v1.y, wv, a[5]);
        a[6]  = fmaf(v1.z, wv, a[6]);  a[7]  = fmaf(v1.w, wv, a[7]);
        a[8]  = fmaf(v2.x, wv, a[8]);  a[9]  = fmaf(v2.y, wv, a[9]);
        a[10] = fmaf(v2.z, wv, a[10]); a[11] = fmaf(v2.w, wv, a[11]);
        a[12] = fmaf(v3.x, wv, a[12]); a[13] = fmaf(v3.y, wv, a[13]);
        a[14] = fmaf(v3.z, wv, a[14]); a[15] = fmaf(v3.w, wv, a[15]);
      }
#pragma unroll
      for (int nl = 0; nl < 16; ++nl) sg[nl * 384 + j2] = a[nl];
    }
  }
  __syncthreads();

  // phase 3: GRU elementwise
#pragma unroll
  for (int i = 0; i < 4; ++i) {
    int idx = i * 256 + t;
    int nl = idx >> 6, dc = idx & 63;
    const float* g = &sg[nl * 384];
    float ir = g[dc], iz = g[64 + dc], in_ = g[128 + dc];
    float hr = g[192 + dc], hz = g[256 + dc], hn = g[320 + dc];
    float r = sigm(ir + hr), z = sigm(iz + hz);
    float nc = tanhf(in_ + r * hn);
    hid[(size_t)nb * 64 + idx] = (1.f - z) * nc + z * shT[dc * 20 + nl];
  }
}

// ---------------------------------------------------------------------------
// edge_mlp (MFMA, fp16): e' = relu(relu([h[row]|h[col]|e] @ We1 + b1) @ We2 + b2)
// 64 edges/block. cat staged to LDS as fp16; B fragments direct from global
// (per-wave disjoint rows). Hidden tile Ts in LDS (fp16). f32 in/out, in place.
// ---------------------------------------------------------------------------
__launch_bounds__(256)
__global__ void edge_mlp_m(const float* __restrict__ hid,
                           float* __restrict__ ebf,
                           const int* __restrict__ eidx,
                           const _Float16* __restrict__ We1T,
                           const float* __restrict__ be1,
                           const _Float16* __restrict__ We2T,
                           const float* __restrict__ be2) {
  __shared__ _Float16 As[64 * 264];   // 33,792 B
  __shared__ _Float16 Ts[64 * 136];   // 17,408 B
  const int t = threadIdx.x;
  const int w = t >> 6, l = t & 63, l15 = l & 15, q = l >> 4;
  const int mbase = blockIdx.x * 64;

  for (int g = t; g < 2048; g += 256) {
    int r = g >> 5, kg = g & 31;
    int e = mbase + r;
    const float* src;
    if (kg < 8)       src = &hid[(size_t)eidx[e] * 64 + kg * 8];
    else if (kg < 16) src = &hid[(size_t)eidx[N_EDGES + e] * 64 + (kg - 8) * 8];
    else              src = &ebf[(size_t)e * 128 + (kg - 16) * 8];
    *(f16x8*)&As[r * 264 + kg * 8] = packh8(src);
  }
  __syncthreads();

  f32x4 zero4 = {0.f, 0.f, 0.f, 0.f};
  f32x4 acc[4][2];
#pragma unroll
  for (int m = 0; m < 4; ++m)
#pragma unroll
    for (int nn = 0; nn < 2; ++nn) acc[m][nn] = zero4;

#pragma unroll
  for (int kc = 0; kc < 4; ++kc)
#pragma unroll
    for (int kk = 0; kk < 2; ++kk) {
      int ko = kc * 64 + kk * 32 + q * 8;
      f16x8 b0 = *(const f16x8*)(We1T + (size_t)(w * 32 + l15) * 256 + ko);
      f16x8 b1 = *(const f16x8*)(We1T + (size_t)(w * 32 + 16 + l15) * 256 + ko);
#pragma unroll
      for (int m = 0; m < 4; ++m) {
        f16x8 a = *(const f16x8*)&As[(m * 16 + l15) * 264 + ko];
        acc[m][0] = __builtin_amdgcn_mfma_f32_16x16x32_f16(a, b0, acc[m][0], 0, 0, 0);
        acc[m][1] = __builtin_amdgcn_mfma_f32_16x16x32_f16(a, b1, acc[m][1], 0, 0, 0);
      }
    }

#pragma unroll
  for (int m = 0; m < 4; ++m)
#pragma unroll
    for (int nn = 0; nn < 2; ++nn) {
      int col = w * 32 + nn * 16 + l15;
      float bv = be1[col];
#pragma unroll
      for (int rr = 0; rr < 4; ++rr) {
        int row = m * 16 + q * 4 + rr;
        Ts[row * 136 + col] = (_Float16)fmaxf(acc[m][nn][rr] + bv, 0.f);
      }
    }
  __syncthreads();

  f32x4 acc2[4][2];
#pragma unroll
  for (int m = 0; m < 4; ++m)
#pragma unroll
    for (int nn = 0; nn < 2; ++nn) acc2[m][nn] = zero4;

#pragma unroll
  for (int kc = 0; kc < 2; ++kc)
#pragma unroll
    for (int kk = 0; kk < 2; ++kk) {
      int ko = kc * 64 + kk * 32 + q * 8;
      f16x8 b0 = *(const f16x8*)(We2T + (size_t)(w * 32 + l15) * 128 + ko);
      f16x8 b1 = *(const f16x8*)(We2T + (size_t)(w * 32 + 16 + l15) * 128 + ko);
#pragma unroll
      for (int m = 0; m < 4; ++m) {
        f16x8 a = *(const f16x8*)&Ts[(m * 16 + l15) * 136 + ko];
        acc2[m][0] = __builtin_amdgcn_mfma_f32_16x16x32_f16(a, b0, acc2[m][0], 0, 0, 0);
        acc2[m][1] = __builtin_amdgcn_mfma_f32_16x16x32_f16(a, b1, acc2[m][1], 0, 0, 0);
      }
    }

#pragma unroll
  for (int m = 0; m < 4; ++m)
#pragma unroll
    for (int nn = 0; nn < 2; ++nn) {
      int col = w * 32 + nn * 16 + l15;
      float bv = be2[col];
#pragma unroll
      for (int rr = 0; rr < 4; ++rr) {
        int row = mbase + m * 16 + q * 4 + rr;
        ebf[(size_t)row * 128 + col] = fmaxf(acc2[m][nn][rr] + bv, 0.f);
      }
    }
}

// ---------------------------------------------------------------------------
extern "C" void kernel_launch(void* const* d_in, const int* in_sizes, int n_in,
                              void* d_out, int out_size, void* d_ws, size_t ws_size,
                              hipStream_t stream) {
  const float* nf    = (const float*)d_in[0];
  const float* ea    = (const float*)d_in[1];
  const int*   eidx  = (const int*)d_in[2];
  const float* Wp    = (const float*)d_in[3];
  const float* bp    = (const float*)d_in[4];
  const float* Wpe   = (const float*)d_in[5];
  const float* bpe   = (const float*)d_in[6];
  const float* Wnn   = (const float*)d_in[7];
  const float* bnn   = (const float*)d_in[8];
  const float* Wroot = (const float*)d_in[9];
  const float* bconv = (const float*)d_in[10];
  const float* wih   = (const float*)d_in[11];
  const float* whh   = (const float*)d_in[12];
  const float* bih   = (const float*)d_in[13];
  const float* bhh   = (const float*)d_in[14];
  const float* We1   = (const float*)d_in[15];
  const float* be1   = (const float*)d_in[16];
  const float* We2   = (const float*)d_in[17];
  const float* be2   = (const float*)d_in[18];

  // h and e live in d_out (f32 masters), fully rewritten every launch.
  float* hid = (float*)d_out;                 // 4096*64
  float* ebf = (float*)d_out + 4096 * 64;     // 32768*128

  // workspace: 5,505,152 B
  char* ws = (char*)d_ws;
  _Float16* WnnT   = (_Float16*)(ws + 0);          // 1,048,576
  _Float16* We1T   = (_Float16*)(ws + 1048576);    //    65,536
  _Float16* We2T   = (_Float16*)(ws + 1114112);    //    32,768
  _Float16* msgbuf = (_Float16*)(ws + 1146880);    // 4,194,304
  int*      rowptr = (int*)(ws + 5341184);         //    16,512 (4097 used)
  int*      cursor = (int*)(ws + 5357696);         //    16,384
  int*      eids   = (int*)(ws + 5374080);         //   131,072

  prep_all<<<320, 256, 0, stream>>>(Wnn, We1, We2, WnnT, We1T, We2T);
  proj_node_f<<<1024, 256, 0, stream>>>(nf, Wp, bp, hid);
  proj_edge_f2<<<1024, 256, 0, stream>>>(ea, Wpe, bpe, ebf);

  // CSR of incoming edges per node (built once; edge_index is constant)
  csr_zero<<<16, 256, 0, stream>>>(cursor);          // use cursor as rowcnt
  csr_count<<<128, 256, 0, stream>>>(eidx, cursor);
  csr_scan<<<1, 1024, 0, stream>>>(cursor, rowptr, cursor);
  csr_fill<<<128, 256, 0, stream>>>(eidx, cursor, eids);

  for (int s = 0; s < 3; ++s) {
    fused_msg_m<<<512, 512, 0, stream>>>(ebf, hid, WnnT, bnn, eidx, msgbuf);
    node_update_g<<<256, 256, 0, stream>>>(msgbuf, rowptr, eids, hid, Wroot, bconv,
                                           wih, whh, bih, bhh);
    edge_mlp_m<<<512, 256, 0, stream>>>(hid, ebf, eidx, We1T, be1, We2T, be2);
  }
}

// Round 2
// 469.259 us; speedup vs baseline: 1.5138x; 1.5138x over previous
//
#include <hip/hip_runtime.h>
#include <stdint.h>

typedef __attribute__((ext_vector_type(8))) _Float16 f16x8;
typedef __attribute__((ext_vector_type(4))) float f32x4;

#define N_NODES 4096
#define N_EDGES 32768

__device__ __forceinline__ float sigm(float x) { return 1.f / (1.f + __expf(-x)); }

// pack 8 consecutive f32 -> f16x8 (RNE)
__device__ __forceinline__ f16x8 packh8(const float* p) {
  f16x8 r;
#pragma unroll
  for (int i = 0; i < 8; ++i) r[i] = (_Float16)p[i];
  return r;
}

// ---------------------------------------------------------------------------
// prep (merged): blocks 0..127  -> WnnT[n][k] fp16 from Wnn[k][n] f32
//                blocks 128..319 -> We1T / We2T fp16 transposes
// ---------------------------------------------------------------------------
__global__ void prep_all(const float* __restrict__ Wnn,
                         const float* __restrict__ We1,
                         const float* __restrict__ We2,
                         _Float16* __restrict__ WnnT,
                         _Float16* __restrict__ We1T,
                         _Float16* __restrict__ We2T) {
  __shared__ float tile[128][33];
  const int b = blockIdx.x, t = threadIdx.x;
  if (b < 128) {
    const int nb = b * 32;
    for (int i = 0; i < 16; ++i) {
      int g = i * 256 + t;          // 4096 = 128k x 32n
      int k = g >> 5, j = g & 31;
      tile[k][j] = Wnn[(size_t)k * 4096 + nb + j];
    }
    __syncthreads();
    for (int i = 0; i < 16; ++i) {
      int g = i * 256 + t;
      int j = g >> 7, k = g & 127;
      WnnT[(size_t)(nb + j) * 128 + k] = (_Float16)tile[k][j];
    }
  } else {
    int idx = (b - 128) * 256 + t;   // < 49152
    if (idx < 32768) {
      int n = idx >> 8, k = idx & 255;
      We1T[idx] = (_Float16)We1[(size_t)k * 128 + n];
    } else {
      int j = idx - 32768;
      int n = j >> 7, k = j & 127;
      We2T[j] = (_Float16)We2[(size_t)k * 128 + n];
    }
  }
}

// ---------------------------------------------------------------------------
// CSR build (once per launch; edge_index is launch-constant)
// ---------------------------------------------------------------------------
__global__ void csr_zero(int* __restrict__ rowcnt) {
  rowcnt[blockIdx.x * 256 + threadIdx.x] = 0;
}
__global__ void csr_count(const int* __restrict__ eidx, int* __restrict__ rowcnt) {
  int e = blockIdx.x * 256 + threadIdx.x;
  atomicAdd(&rowcnt[eidx[N_EDGES + e]], 1);
}
__global__ void csr_scan(const int* __restrict__ rowcnt,
                         int* __restrict__ rowptr, int* __restrict__ cursor) {
  __shared__ int part[1024];
  const int t = threadIdx.x;
  const int base = t * 4;
  int s0 = rowcnt[base], s1 = rowcnt[base + 1], s2 = rowcnt[base + 2], s3 = rowcnt[base + 3];
  int sum = s0 + s1 + s2 + s3;
  part[t] = sum;
  __syncthreads();
  for (int off = 1; off < 1024; off <<= 1) {
    int v = (t >= off) ? part[t - off] : 0;
    __syncthreads();
    part[t] += v;
    __syncthreads();
  }
  int excl = part[t] - sum;
  int p0 = excl, p1 = excl + s0, p2 = excl + s0 + s1, p3 = excl + s0 + s1 + s2;
  rowptr[base] = p0; rowptr[base + 1] = p1; rowptr[base + 2] = p2; rowptr[base + 3] = p3;
  cursor[base] = p0; cursor[base + 1] = p1; cursor[base + 2] = p2; cursor[base + 3] = p3;
  if (t == 0) rowptr[4096] = N_EDGES;
}
__global__ void csr_fill(const int* __restrict__ eidx, int* __restrict__ cursor,
                         int* __restrict__ eids) {
  int e = blockIdx.x * 256 + threadIdx.x;
  int slot = atomicAdd(&cursor[eidx[N_EDGES + e]], 1);
  eids[slot] = e;
}

// ---------------------------------------------------------------------------
// proj_node: h = relu(node_feats @ W_p + b_p) -> hid f32 (in d_out)
// ---------------------------------------------------------------------------
__global__ void proj_node_f(const float* __restrict__ nf,
                            const float* __restrict__ Wp,
                            const float* __restrict__ bp,
                            float* __restrict__ h) {
  int idx = blockIdx.x * 256 + threadIdx.x;
  int n = idx >> 6, c = idx & 63;
  float acc = bp[c];
  for (int k = 0; k < 64; ++k)
    acc = fmaf(nf[n * 64 + k], Wp[k * 64 + c], acc);
  h[idx] = fmaxf(acc, 0.f);
}

// ---------------------------------------------------------------------------
// proj_edge: e = relu(edge_attr @ W_pe + b_pe); Wpe cached in LDS; 32 e/block.
// ---------------------------------------------------------------------------
__launch_bounds__(256)
__global__ void proj_edge_f2(const float* __restrict__ ea,
                             const float* __restrict__ Wpe,
                             const float* __restrict__ bpe,
                             float* __restrict__ e) {
  __shared__ float sw[16 * 128];
  __shared__ float sb[128];
  __shared__ float sa[32][17];
  const int t = threadIdx.x;
  const int ebase = blockIdx.x * 32;
  for (int g = t; g < 2048; g += 256) sw[g] = Wpe[g];
  if (t < 128) sb[t] = bpe[t];
  for (int g = t; g < 512; g += 256) {
    int r = g >> 4, k = g & 15;
    sa[r][k] = ea[(size_t)(ebase + r) * 16 + k];
  }
  __syncthreads();
  int c = t & 127, eg = t >> 7;
  float wc[16];
#pragma unroll
  for (int k = 0; k < 16; ++k) wc[k] = sw[k * 128 + c];
  float bv = sb[c];
#pragma unroll
  for (int i = 0; i < 16; ++i) {
    int ee = eg * 16 + i;
    float acc = bv;
#pragma unroll
    for (int k = 0; k < 16; ++k) acc = fmaf(sa[ee][k], wc[k], acc);
    e[(size_t)(ebase + ee) * 128 + c] = fmaxf(acc, 0.f);
  }
}

// ---------------------------------------------------------------------------
// fused_msg (MFMA fp16 v10): 512 blocks x 512 threads, 64 edges/block.
// R13 post-mortem: v9's launch_bounds(512,4) acted as minBlocksPerCU=4 ->
// 64-VGPR cap -> massive scratch spills (WRITE 4->128MB, FETCH 15->333MB,
// HBM-bound at 160us). The occupancy gain itself was real (20.7->43.6%).
// v10: identical structure, launch_bounds(512,2) -> 128-VGPR cap; natural
// ~116 VGPRs fit, 2 blocks/CU = 4 waves/SIMD, zero spill.
// Kept: per-wave d-half split (8 waves = 4 f-groups x 2 d-halves, LDS
// reduce), per-wave dg rotation, opaque A-LDS offset, bnn in MFMA C-init,
// XOR-swizzled Ae.
// ---------------------------------------------------------------------------
__launch_bounds__(512, 2)
__global__ void fused_msg_m(const float* __restrict__ ebf,
                            const float* __restrict__ hid,
                            const _Float16* __restrict__ WnnT,
                            const float* __restrict__ bnn,
                            const int* __restrict__ eidx,
                            _Float16* __restrict__ msgbuf) {
  __shared__ __align__(16) _Float16 Ae[64 * 128];  // 16,384 B, XOR-swizzled
  __shared__ __align__(16) float Hs[64 * 68];      // 17,408 B  Hs[d*68+e]
  __shared__ __align__(16) float Rd[64 * 66];      // 16,896 B  d-half reduce
  const int t = threadIdx.x;       // 0..511
  const int w = t >> 6, l = t & 63, l15 = l & 15, q = l >> 4;
  const int fw = w & 3;            // f cols: fw*16 + l15
  const int dh = w >> 2;           // d half: d in [dh*32, dh*32+32)
  const int ebase = blockIdx.x * 64;
  const int rot = (blockIdx.x * 2 + w) & 7;   // per-WAVE rotation

  // stage Hs (transposed): 64 e x 16 d-quads
#pragma unroll
  for (int i = 0; i < 2; ++i) {
    int g = i * 512 + t;
    int e = g >> 4, d4 = g & 15;
    int r = eidx[ebase + e];
    float4 v = *(const float4*)&hid[(size_t)r * 64 + d4 * 4];
    Hs[(d4 * 4 + 0) * 68 + e] = v.x;
    Hs[(d4 * 4 + 1) * 68 + e] = v.y;
    Hs[(d4 * 4 + 2) * 68 + e] = v.z;
    Hs[(d4 * 4 + 3) * 68 + e] = v.w;
  }
  // stage Ae: 64 edges x 128 k, f32 -> fp16 once, XOR-swizzled 16B blocks
#pragma unroll
  for (int i = 0; i < 2; ++i) {
    int g = i * 512 + t;           // 1024 = 64 e x 16 groups of 8 halves
    int e = g >> 4, kg = g & 15;
    f16x8 v = packh8(&ebf[(size_t)(ebase + e) * 128 + kg * 8]);
    int kgp = kg ^ (e & 15);
    *(f16x8*)&Ae[e * 128 + kgp * 8] = v;
  }

  float msg[4][4];
#pragma unroll
  for (int m = 0; m < 4; ++m)
#pragma unroll
    for (int rr = 0; rr < 4; ++rr) msg[m][rr] = 0.f;

  __syncthreads();

  // opaque zero: A-LDS addresses depend on it -> reads can't be hoisted out
  // of the dg loop (avoids the 64-VGPR A-hoist), but B loads CAN pipeline.
  int aoff = 0;
  asm volatile("" : "+v"(aoff));

  // B fragment base: lane row within chunk = fw*16+l15, k-offset q*8
  const _Float16* wb = WnnT + (size_t)(fw * 16 + l15) * 128 + q * 8;

#pragma unroll 1
  for (int dgi = 0; dgi < 8; ++dgi) {
    const int dgr = dh * 8 + ((dgi + rot) & 7);   // this wave's d-half sweep
    f16x8 bb[4][4];
#pragma unroll
    for (int c = 0; c < 4; ++c) {
      const _Float16* p = wb + (size_t)(dgr * 4 + c) * 8192;
#pragma unroll
      for (int kk = 0; kk < 4; ++kk) bb[c][kk] = *(const f16x8*)(p + kk * 32);
    }
    float bnv[4];
#pragma unroll
    for (int c = 0; c < 4; ++c) bnv[c] = bnn[(dgr * 4 + c) * 64 + fw * 16 + l15];

#pragma unroll
    for (int m = 0; m < 4; ++m) {
      const int arow = (m * 16 + l15) * 128 + aoff;
      f32x4 C[4];
#pragma unroll
      for (int c = 0; c < 4; ++c)
        C[c] = (f32x4){bnv[c], bnv[c], bnv[c], bnv[c]};   // bias pre-loaded
#pragma unroll
      for (int kk = 0; kk < 4; ++kk) {
        int kgp = (kk * 4 + q) ^ l15;   // e&15 == l15 for this wave's A rows
        f16x8 a = *(const f16x8*)&Ae[arow + kgp * 8];
#pragma unroll
        for (int c = 0; c < 4; ++c)
          C[c] = __builtin_amdgcn_mfma_f32_16x16x32_f16(a, bb[c][kk], C[c], 0, 0, 0);
      }
#pragma unroll
      for (int c = 0; c < 4; ++c) {
        int d = dgr * 4 + c;
        float4 hv = *(const float4*)&Hs[d * 68 + m * 16 + q * 4];
        msg[m][0] = fmaf(hv.x, fmaxf(C[c][0], 0.f), msg[m][0]);
        msg[m][1] = fmaf(hv.y, fmaxf(C[c][1], 0.f), msg[m][1]);
        msg[m][2] = fmaf(hv.z, fmaxf(C[c][2], 0.f), msg[m][2]);
        msg[m][3] = fmaf(hv.w, fmaxf(C[c][3], 0.f), msg[m][3]);
      }
    }
  }

  // cross-d-half reduction via LDS, then plain fp16 stores -> msgbuf[e][f]
  if (dh == 1) {
#pragma unroll
    for (int m = 0; m < 4; ++m)
#pragma unroll
      for (int rr = 0; rr < 4; ++rr)
        Rd[(m * 16 + q * 4 + rr) * 66 + fw * 16 + l15] = msg[m][rr];
  }
  __syncthreads();
  if (dh == 0) {
#pragma unroll
    for (int m = 0; m < 4; ++m)
#pragma unroll
      for (int rr = 0; rr < 4; ++rr) {
        int er = m * 16 + q * 4 + rr;
        float v = msg[m][rr] + Rd[er * 66 + fw * 16 + l15];
        msgbuf[(size_t)(ebase + er) * 64 + fw * 16 + l15] = (_Float16)v;
      }
  }
}

// ---------------------------------------------------------------------------
// node_update_g: agg via CSR gather of msgbuf; m = relu(agg + h@W_root+b);
// GRU gates gate-column-per-thread (weights read once per block); h (f32,
// d_out) updated in place. Block = 16 nodes, 256 threads.
// ---------------------------------------------------------------------------
__launch_bounds__(256)
__global__ void node_update_g(const _Float16* __restrict__ msgbuf,
                              const int* __restrict__ rowptr,
                              const int* __restrict__ eids,
                              float* __restrict__ hid,
                              const float* __restrict__ Wroot,
                              const float* __restrict__ bconv,
                              const float* __restrict__ wih,
                              const float* __restrict__ whh,
                              const float* __restrict__ bih,
                              const float* __restrict__ bhh) {
  __shared__ __align__(16) float shT[64 * 20];   // h^T  [k][nl], stride 20
  __shared__ __align__(16) float smT[64 * 20];   // m^T  [k][nl]
  __shared__ __align__(16) float sg[16 * 384];   // gates
  __shared__ __align__(16) float sW[64 * 64];    // Wroot
  const int t = threadIdx.x;
  const int nb = blockIdx.x * 16;

  // stage Wroot (f32, 16KB)
#pragma unroll
  for (int i = 0; i < 4; ++i) {
    int g = i * 256 + t;
    *(float4*)&sW[g * 4] = *(const float4*)&Wroot[g * 4];
  }
  // stage h transposed
#pragma unroll
  for (int i = 0; i < 4; ++i) {
    int idx = i * 256 + t;
    int nl = idx >> 6, dc = idx & 63;
    shT[dc * 20 + nl] = hid[(size_t)(nb + nl) * 64 + dc];
  }
  __syncthreads();

  // phase 1: gather msg + root matmul -> m (write transposed)
#pragma unroll
  for (int i = 0; i < 4; ++i) {
    int idx = i * 256 + t;
    int nl = idx >> 6, dc = idx & 63;
    int n = nb + nl;
    float acc = bconv[dc];
    int r0 = rowptr[n], r1 = rowptr[n + 1];
    for (int j = r0; j < r1; ++j)
      acc += (float)msgbuf[(size_t)eids[j] * 64 + dc];
    for (int k = 0; k < 64; ++k)
      acc = fmaf(shT[k * 20 + nl], sW[k * 64 + dc], acc);
    smT[dc * 20 + nl] = fmaxf(acc, 0.f);
  }
  __syncthreads();

  // phase 2: gates — thread owns one gate column, accumulates 16 nodes in regs
  for (int p = 0; p < 2; ++p) {
    int j2 = p * 256 + t;
    if (j2 < 384) {
      bool is_ih = (j2 < 192);
      int col = is_ih ? j2 : j2 - 192;
      const float* W = is_ih ? wih : whh;
      float bias = is_ih ? bih[col] : bhh[col];
      const float* inT = is_ih ? smT : shT;
      float a[16];
#pragma unroll
      for (int nl = 0; nl < 16; ++nl) a[nl] = bias;
      for (int k = 0; k < 64; ++k) {
        float wv = W[k * 192 + col];
        float4 v0 = *(const float4*)&inT[k * 20 + 0];
        float4 v1 = *(const float4*)&inT[k * 20 + 4];
        float4 v2 = *(const float4*)&inT[k * 20 + 8];
        float4 v3 = *(const float4*)&inT[k * 20 + 12];
        a[0]  = fmaf(v0.x, wv, a[0]);  a[1]  = fmaf(v0.y, wv, a[1]);
        a[2]  = fmaf(v0.z, wv, a[2]);  a[3]  = fmaf(v0.w, wv, a[3]);
        a[4]  = fmaf(v1.x, wv, a[4]);  a[5]  = fmaf(v1.y, wv, a[5]);
        a[6]  = fmaf(v1.z, wv, a[6]);  a[7]  = fmaf(v1.w, wv, a[7]);
        a[8]  = fmaf(v2.x, wv, a[8]);  a[9]  = fmaf(v2.y, wv, a[9]);
        a[10] = fmaf(v2.z, wv, a[10]); a[11] = fmaf(v2.w, wv, a[11]);
        a[12] = fmaf(v3.x, wv, a[12]); a[13] = fmaf(v3.y, wv, a[13]);
        a[14] = fmaf(v3.z, wv, a[14]); a[15] = fmaf(v3.w, wv, a[15]);
      }
#pragma unroll
      for (int nl = 0; nl < 16; ++nl) sg[nl * 384 + j2] = a[nl];
    }
  }
  __syncthreads();

  // phase 3: GRU elementwise
#pragma unroll
  for (int i = 0; i < 4; ++i) {
    int idx = i * 256 + t;
    int nl = idx >> 6, dc = idx & 63;
    const float* g = &sg[nl * 384];
    float ir = g[dc], iz = g[64 + dc], in_ = g[128 + dc];
    float hr = g[192 + dc], hz = g[256 + dc], hn = g[320 + dc];
    float r = sigm(ir + hr), z = sigm(iz + hz);
    float nc = tanhf(in_ + r * hn);
    hid[(size_t)nb * 64 + idx] = (1.f - z) * nc + z * shT[dc * 20 + nl];
  }
}

// ---------------------------------------------------------------------------
// edge_mlp (MFMA, fp16): e' = relu(relu([h[row]|h[col]|e] @ We1 + b1) @ We2 + b2)
// 64 edges/block. cat staged to LDS as fp16; B fragments direct from global
// (per-wave disjoint rows). Hidden tile Ts in LDS (fp16). f32 in/out, in place.
// ---------------------------------------------------------------------------
__launch_bounds__(256)
__global__ void edge_mlp_m(const float* __restrict__ hid,
                           float* __restrict__ ebf,
                           const int* __restrict__ eidx,
                           const _Float16* __restrict__ We1T,
                           const float* __restrict__ be1,
                           const _Float16* __restrict__ We2T,
                           const float* __restrict__ be2) {
  __shared__ _Float16 As[64 * 264];   // 33,792 B
  __shared__ _Float16 Ts[64 * 136];   // 17,408 B
  const int t = threadIdx.x;
  const int w = t >> 6, l = t & 63, l15 = l & 15, q = l >> 4;
  const int mbase = blockIdx.x * 64;

  for (int g = t; g < 2048; g += 256) {
    int r = g >> 5, kg = g & 31;
    int e = mbase + r;
    const float* src;
    if (kg < 8)       src = &hid[(size_t)eidx[e] * 64 + kg * 8];
    else if (kg < 16) src = &hid[(size_t)eidx[N_EDGES + e] * 64 + (kg - 8) * 8];
    else              src = &ebf[(size_t)e * 128 + (kg - 16) * 8];
    *(f16x8*)&As[r * 264 + kg * 8] = packh8(src);
  }
  __syncthreads();

  f32x4 zero4 = {0.f, 0.f, 0.f, 0.f};
  f32x4 acc[4][2];
#pragma unroll
  for (int m = 0; m < 4; ++m)
#pragma unroll
    for (int nn = 0; nn < 2; ++nn) acc[m][nn] = zero4;

#pragma unroll
  for (int kc = 0; kc < 4; ++kc)
#pragma unroll
    for (int kk = 0; kk < 2; ++kk) {
      int ko = kc * 64 + kk * 32 + q * 8;
      f16x8 b0 = *(const f16x8*)(We1T + (size_t)(w * 32 + l15) * 256 + ko);
      f16x8 b1 = *(const f16x8*)(We1T + (size_t)(w * 32 + 16 + l15) * 256 + ko);
#pragma unroll
      for (int m = 0; m < 4; ++m) {
        f16x8 a = *(const f16x8*)&As[(m * 16 + l15) * 264 + ko];
        acc[m][0] = __builtin_amdgcn_mfma_f32_16x16x32_f16(a, b0, acc[m][0], 0, 0, 0);
        acc[m][1] = __builtin_amdgcn_mfma_f32_16x16x32_f16(a, b1, acc[m][1], 0, 0, 0);
      }
    }

#pragma unroll
  for (int m = 0; m < 4; ++m)
#pragma unroll
    for (int nn = 0; nn < 2; ++nn) {
      int col = w * 32 + nn * 16 + l15;
      float bv = be1[col];
#pragma unroll
      for (int rr = 0; rr < 4; ++rr) {
        int row = m * 16 + q * 4 + rr;
        Ts[row * 136 + col] = (_Float16)fmaxf(acc[m][nn][rr] + bv, 0.f);
      }
    }
  __syncthreads();

  f32x4 acc2[4][2];
#pragma unroll
  for (int m = 0; m < 4; ++m)
#pragma unroll
    for (int nn = 0; nn < 2; ++nn) acc2[m][nn] = zero4;

#pragma unroll
  for (int kc = 0; kc < 2; ++kc)
#pragma unroll
    for (int kk = 0; kk < 2; ++kk) {
      int ko = kc * 64 + kk * 32 + q * 8;
      f16x8 b0 = *(const f16x8*)(We2T + (size_t)(w * 32 + l15) * 128 + ko);
      f16x8 b1 = *(const f16x8*)(We2T + (size_t)(w * 32 + 16 + l15) * 128 + ko);
#pragma unroll
      for (int m = 0; m < 4; ++m) {
        f16x8 a = *(const f16x8*)&Ts[(m * 16 + l15) * 136 + ko];
        acc2[m][0] = __builtin_amdgcn_mfma_f32_16x16x32_f16(a, b0, acc2[m][0], 0, 0, 0);
        acc2[m][1] = __builtin_amdgcn_mfma_f32_16x16x32_f16(a, b1, acc2[m][1], 0, 0, 0);
      }
    }

#pragma unroll
  for (int m = 0; m < 4; ++m)
#pragma unroll
    for (int nn = 0; nn < 2; ++nn) {
      int col = w * 32 + nn * 16 + l15;
      float bv = be2[col];
#pragma unroll
      for (int rr = 0; rr < 4; ++rr) {
        int row = mbase + m * 16 + q * 4 + rr;
        ebf[(size_t)row * 128 + col] = fmaxf(acc2[m][nn][rr] + bv, 0.f);
      }
    }
}

// ---------------------------------------------------------------------------
extern "C" void kernel_launch(void* const* d_in, const int* in_sizes, int n_in,
                              void* d_out, int out_size, void* d_ws, size_t ws_size,
                              hipStream_t stream) {
  const float* nf    = (const float*)d_in[0];
  const float* ea    = (const float*)d_in[1];
  const int*   eidx  = (const int*)d_in[2];
  const float* Wp    = (const float*)d_in[3];
  const float* bp    = (const float*)d_in[4];
  const float* Wpe   = (const float*)d_in[5];
  const float* bpe   = (const float*)d_in[6];
  const float* Wnn   = (const float*)d_in[7];
  const float* bnn   = (const float*)d_in[8];
  const float* Wroot = (const float*)d_in[9];
  const float* bconv = (const float*)d_in[10];
  const float* wih   = (const float*)d_in[11];
  const float* whh   = (const float*)d_in[12];
  const float* bih   = (const float*)d_in[13];
  const float* bhh   = (const float*)d_in[14];
  const float* We1   = (const float*)d_in[15];
  const float* be1   = (const float*)d_in[16];
  const float* We2   = (const float*)d_in[17];
  const float* be2   = (const float*)d_in[18];

  // h and e live in d_out (f32 masters), fully rewritten every launch.
  float* hid = (float*)d_out;                 // 4096*64
  float* ebf = (float*)d_out + 4096 * 64;     // 32768*128

  // workspace: 5,505,152 B
  char* ws = (char*)d_ws;
  _Float16* WnnT   = (_Float16*)(ws + 0);          // 1,048,576
  _Float16* We1T   = (_Float16*)(ws + 1048576);    //    65,536
  _Float16* We2T   = (_Float16*)(ws + 1114112);    //    32,768
  _Float16* msgbuf = (_Float16*)(ws + 1146880);    // 4,194,304
  int*      rowptr = (int*)(ws + 5341184);         //    16,512 (4097 used)
  int*      cursor = (int*)(ws + 5357696);         //    16,384
  int*      eids   = (int*)(ws + 5374080);         //   131,072

  prep_all<<<320, 256, 0, stream>>>(Wnn, We1, We2, WnnT, We1T, We2T);
  proj_node_f<<<1024, 256, 0, stream>>>(nf, Wp, bp, hid);
  proj_edge_f2<<<1024, 256, 0, stream>>>(ea, Wpe, bpe, ebf);

  // CSR of incoming edges per node (built once; edge_index is constant)
  csr_zero<<<16, 256, 0, stream>>>(cursor);          // use cursor as rowcnt
  csr_count<<<128, 256, 0, stream>>>(eidx, cursor);
  csr_scan<<<1, 1024, 0, stream>>>(cursor, rowptr, cursor);
  csr_fill<<<128, 256, 0, stream>>>(eidx, cursor, eids);

  for (int s = 0; s < 3; ++s) {
    fused_msg_m<<<512, 512, 0, stream>>>(ebf, hid, WnnT, bnn, eidx, msgbuf);
    node_update_g<<<256, 256, 0, stream>>>(msgbuf, rowptr, eids, hid, Wroot, bconv,
                                           wih, whh, bih, bhh);
    edge_mlp_m<<<512, 256, 0, stream>>>(hid, ebf, eidx, We1T, be1, We2T, be2);
  }
}